// Round 10
// baseline (224.891 us; speedup 1.0000x reference)
//
#include <hip/hip_runtime.h>

// Problem sizes
#define NB  131072   // batch
#define ND1 40       // features (GEMM K)
#define ND2 10       // timesteps
#define NT0 120      // template rows (GEMM M, padded to 128)
#define NT1 5        // u
#define NO0 3        // outputs

#define NBW 64       // batches per workgroup (GEMM N)
#define PK  40       // Ybf row pitch in bf16 elems (80 B, 16B-aligned)

typedef __attribute__((ext_vector_type(8))) short  short8;  // 8 bf16 = MFMA A/B frag
typedef __attribute__((ext_vector_type(4))) float  f32x4;   // MFMA C/D frag

static __device__ __forceinline__ unsigned short f2bf(float f) {
    union { float f; unsigned u; } v; v.f = f;
    unsigned r = v.u + 0x7FFFu + ((v.u >> 16) & 1u);   // round-to-nearest-even
    return (unsigned short)(r >> 16);
}

// Per 64-batch tile:
//  phase 1 (VALU fp32): y[d][u] streamed chunk-by-chunk into LDS as bf16
//          (no register-resident y array -> no scratch spill).
//  phase 2 (MFMA bf16): per u: Z[t,b] = sum_d W11[t,d]*Y_u[d,b] via two
//          mfma_f32_16x16x32_bf16 (k-tile 1 masked to cols 32..39);
//          fused st[t,b] += fc4[u]*relu(Z+bias1[t,u]).
//  epilogue: out[o,b] = sum_t W12[o,t]*st[t,b].
__global__ __launch_bounds__(256, 4) void BL_36721970381090_kernel(
    const float* __restrict__ x,
    const float* __restrict__ W11,
    const float* __restrict__ fc2_w,
    const float* __restrict__ bias1,
    const float* __restrict__ W12,
    const float* __restrict__ fc4_w,
    const float* __restrict__ bias2,
    float* __restrict__ out)
{
    __shared__ __align__(16) unsigned short Ybf[NT1 * NBW * PK];  // 25600 B
    __shared__ float redL[4 * NO0 * NBW];                         //  3072 B

    const int tid = threadIdx.x;
    const int wg  = blockIdx.x;

    // ---------------- phase 1: stream y chunks to LDS ---------------------
    {
        const int bl = tid >> 2;                    // batch slot 0..63
        const int q  = tid & 3;                     // d-quarter (rows q*10..+9)
        const float* xb = x + (size_t)(wg * NBW + bl) * (ND1 * ND2) + q * 100;
        unsigned* YbfW = (unsigned*)Ybf;
        const int dbase = bl * (PK / 2) + q * 5;    // dword index within u-plane

#pragma unroll
        for (int g = 0; g < 5; ++g) {               // 2 d-rows (20 floats)/chunk
            float4 xv[5];
            const float4* p = (const float4*)(xb + g * 20);
#pragma unroll
            for (int i = 0; i < 5; ++i) xv[i] = p[i];
            const float* xs = (const float*)xv;
#pragma unroll
            for (int u = 0; u < NT1; ++u) {
                float a0 = 0.f, a1 = 0.f;
#pragma unroll
                for (int s = 0; s < ND2; ++s) {
                    const float fw = fc2_w[u * ND2 + s];
                    a0 = fmaf(xs[s], fw, a0);
                    a1 = fmaf(xs[ND2 + s], fw, a1);
                }
                YbfW[u * (NBW * PK / 2) + dbase + g] =
                    (unsigned)f2bf(a0) | ((unsigned)f2bf(a1) << 16);
            }
        }
    }

    // ---------------- A-fragments: W11 -> bf16, masked (t<120, d<40) ------
    const int w  = tid >> 6;    // wave 0..3: t-rows [w*32, w*32+32)
    const int l  = tid & 63;
    const int lr = l & 15;      // A row / B col within 16-tile
    const int lg = l >> 4;      // k-group (8 contiguous k per group)

    short8 afr[2][2];           // [m-tile][k-tile]
#pragma unroll
    for (int mt = 0; mt < 2; ++mt) {
        const int t  = w * 32 + mt * 16 + lr;
        const int tc = t < NT0 ? t : NT0 - 1;
#pragma unroll
        for (int kk = 0; kk < 2; ++kk) {
            const int cb = kk * 32 + lg * 8;        // k-base 0..56
            const int cc = cb <= 32 ? cb : 0;       // clamp (row is 40 wide)
            const float4* pw = (const float4*)(W11 + tc * ND1 + cc);
            const float4 w0 = pw[0], w1 = pw[1];
            const bool v = (t < NT0) && (cb <= 32); // valid cols only
            short8 f;
            f[0] = v ? (short)f2bf(w0.x) : (short)0;
            f[1] = v ? (short)f2bf(w0.y) : (short)0;
            f[2] = v ? (short)f2bf(w0.z) : (short)0;
            f[3] = v ? (short)f2bf(w0.w) : (short)0;
            f[4] = v ? (short)f2bf(w1.x) : (short)0;
            f[5] = v ? (short)f2bf(w1.y) : (short)0;
            f[6] = v ? (short)f2bf(w1.z) : (short)0;
            f[7] = v ? (short)f2bf(w1.w) : (short)0;
            afr[mt][kk] = f;
        }
    }

    __syncthreads();

    // ---------------- phase 2: MFMA + fused relu/fc4 ----------------------
    float st[2][4][4];          // [m-tile][n-tile][reg] = st[t, b] fragments
#pragma unroll
    for (int mt = 0; mt < 2; ++mt)
#pragma unroll
        for (int nt = 0; nt < 4; ++nt)
#pragma unroll
            for (int r = 0; r < 4; ++r) st[mt][nt][r] = 0.f;

    const short8 zfrag = {0, 0, 0, 0, 0, 0, 0, 0};

#pragma unroll
    for (int u = 0; u < NT1; ++u) {
        const float fu = fc4_w[u];                  // wave-uniform scalar
        float bv[2][4];
#pragma unroll
        for (int mt = 0; mt < 2; ++mt)
#pragma unroll
            for (int r = 0; r < 4; ++r) {
                const int t = w * 32 + mt * 16 + lg * 4 + r;
                bv[mt][r] = (t < NT0) ? bias1[t * NT1 + u] : 0.f;
            }
        const unsigned short* Yu = &Ybf[u * (NBW * PK)];
#pragma unroll
        for (int nt = 0; nt < 4; ++nt) {
            const short8 b0 = *(const short8*)&Yu[(nt * 16 + lr) * PK + lg * 8];
            short8 b1 = zfrag;                       // k-tile 1: cols 32..39
            if (lg == 0)                             // only k-group 0 is real
                b1 = *(const short8*)&Yu[(nt * 16 + lr) * PK + 32];
#pragma unroll
            for (int mt = 0; mt < 2; ++mt) {
                f32x4 z = {0.f, 0.f, 0.f, 0.f};
                z = __builtin_amdgcn_mfma_f32_16x16x32_bf16(afr[mt][0], b0, z, 0, 0, 0);
                z = __builtin_amdgcn_mfma_f32_16x16x32_bf16(afr[mt][1], b1, z, 0, 0, 0);
#pragma unroll
                for (int r = 0; r < 4; ++r)
                    st[mt][nt][r] += fu * fmaxf(z[r] + bv[mt][r], 0.f);
            }
        }
    }

    // ---------------- epilogue: out[o,b] = sum_t W12[o,t]*st[t,b] ---------
    float w12v[NO0][2][4];
#pragma unroll
    for (int o = 0; o < NO0; ++o)
#pragma unroll
        for (int mt = 0; mt < 2; ++mt)
#pragma unroll
            for (int r = 0; r < 4; ++r) {
                const int t = w * 32 + mt * 16 + lg * 4 + r;
                w12v[o][mt][r] = (t < NT0) ? W12[o * NT0 + t] : 0.f;
            }

    float po[4][NO0];
#pragma unroll
    for (int nt = 0; nt < 4; ++nt)
#pragma unroll
        for (int o = 0; o < NO0; ++o) {
            float a = 0.f;
#pragma unroll
            for (int mt = 0; mt < 2; ++mt)
#pragma unroll
                for (int r = 0; r < 4; ++r)
                    a = fmaf(w12v[o][mt][r], st[mt][nt][r], a);
            a += __shfl_xor(a, 16, 64);   // reduce over k-groups (t-rows)
            a += __shfl_xor(a, 32, 64);
            po[nt][o] = a;
        }

    if (l < 16) {
#pragma unroll
        for (int nt = 0; nt < 4; ++nt)
#pragma unroll
            for (int o = 0; o < NO0; ++o)
                redL[(w * NO0 + o) * NBW + nt * 16 + l] = po[nt][o];
    }
    __syncthreads();

    if (tid < NO0 * NBW) {                 // 192 threads
        const int o  = tid >> 6;
        const int bc = tid & 63;
        const float s = redL[(0 * NO0 + o) * NBW + bc]
                      + redL[(1 * NO0 + o) * NBW + bc]
                      + redL[(2 * NO0 + o) * NBW + bc]
                      + redL[(3 * NO0 + o) * NBW + bc]
                      + bias2[o];
        out[(size_t)(wg * NBW + bc) * NO0 + o] = s;
    }
}

extern "C" void kernel_launch(void* const* d_in, const int* in_sizes, int n_in,
                              void* d_out, int out_size, void* d_ws, size_t ws_size,
                              hipStream_t stream) {
    const float* x      = (const float*)d_in[0];
    const float* W11    = (const float*)d_in[1];
    const float* fc2_w  = (const float*)d_in[2];
    const float* bias1  = (const float*)d_in[3];
    const float* W12    = (const float*)d_in[4];
    const float* fc4_w  = (const float*)d_in[5];
    const float* bias2  = (const float*)d_in[6];
    float* out = (float*)d_out;

    const int blocks = NB / NBW;   // 2048
    BL_36721970381090_kernel<<<blocks, 256, 0, stream>>>(
        x, W11, fc2_w, bias1, W12, fc4_w, bias2, out);
}

// Round 11
// 74.622 us; speedup vs baseline: 3.0137x; 3.0137x over previous
//
#include <hip/hip_runtime.h>

// Problem sizes
#define NB  131072   // batch
#define ND1 40       // features (GEMM K)
#define ND2 10       // timesteps
#define NT0 120      // template rows (GEMM M, padded to 128)
#define NT1 5        // u
#define NO0 3        // outputs

#define NBW 64       // batches per workgroup (GEMM N)
#define PK  40       // Ybf row pitch in bf16 elems (80 B, 16B-aligned)

typedef __attribute__((ext_vector_type(8))) short  short8;  // 8 bf16 = MFMA A/B frag
typedef __attribute__((ext_vector_type(4))) float  f32x4;   // MFMA C/D frag

static __device__ __forceinline__ unsigned short f2bf(float f) {
    union { float f; unsigned u; } v; v.f = f;
    unsigned r = v.u + 0x7FFFu + ((v.u >> 16) & 1u);   // round-to-nearest-even
    return (unsigned short)(r >> 16);
}

// Per 64-batch tile:
//  phase 1 (VALU fp32): y[d][u] streamed chunk-by-chunk into LDS as bf16.
//  phase 2 (MFMA bf16): per u: Z[t,b] = sum_d W11[t,d]*Y_u[d,b] via two
//          mfma_f32_16x16x32_bf16 (k-tile 1 masked to cols 32..39);
//          fused st[t,b] += fc4[u]*relu(Z+bias1[t,u]).
//  epilogue: out[o,b] = sum_t W12[o,t]*st[t,b].
//
// __launch_bounds__(256,2): hipcc caps VGPRs at 256/min_waves. (256,4) gave
// a 64-reg cap -> hot-loop spill (WRITE_SIZE 363 MB, 2x slowdown). The
// phase-2 live set is ~100 regs; (256,2) -> 128-reg budget, no spill.
__global__ __launch_bounds__(256, 2) void BL_36721970381090_kernel(
    const float* __restrict__ x,
    const float* __restrict__ W11,
    const float* __restrict__ fc2_w,
    const float* __restrict__ bias1,
    const float* __restrict__ W12,
    const float* __restrict__ fc4_w,
    const float* __restrict__ bias2,
    float* __restrict__ out)
{
    __shared__ __align__(16) unsigned short Ybf[NT1 * NBW * PK];  // 25600 B
    __shared__ float redL[4 * NO0 * NBW];                         //  3072 B

    const int tid = threadIdx.x;
    const int wg  = blockIdx.x;

    // ---------------- phase 1: stream y chunks to LDS ---------------------
    {
        const int bl = tid >> 2;                    // batch slot 0..63
        const int q  = tid & 3;                     // d-quarter (rows q*10..+9)
        const float* xb = x + (size_t)(wg * NBW + bl) * (ND1 * ND2) + q * 100;
        unsigned* YbfW = (unsigned*)Ybf;
        const int dbase = bl * (PK / 2) + q * 5;    // dword index within u-plane

#pragma unroll
        for (int g = 0; g < 5; ++g) {               // 2 d-rows (20 floats)/chunk
            float4 xv[5];
            const float4* p = (const float4*)(xb + g * 20);
#pragma unroll
            for (int i = 0; i < 5; ++i) xv[i] = p[i];
            const float* xs = (const float*)xv;
#pragma unroll
            for (int u = 0; u < NT1; ++u) {
                float a0 = 0.f, a1 = 0.f;
#pragma unroll
                for (int s = 0; s < ND2; ++s) {
                    const float fw = fc2_w[u * ND2 + s];
                    a0 = fmaf(xs[s], fw, a0);
                    a1 = fmaf(xs[ND2 + s], fw, a1);
                }
                YbfW[u * (NBW * PK / 2) + dbase + g] =
                    (unsigned)f2bf(a0) | ((unsigned)f2bf(a1) << 16);
            }
        }
    }

    // ---------------- A-fragments: W11 -> bf16, masked (t<120, d<40) ------
    const int w  = tid >> 6;    // wave 0..3: t-rows [w*32, w*32+32)
    const int l  = tid & 63;
    const int lr = l & 15;      // A row / B col within 16-tile
    const int lg = l >> 4;      // k-group (8 contiguous k per group)

    short8 afr[2][2];           // [m-tile][k-tile]
#pragma unroll
    for (int mt = 0; mt < 2; ++mt) {
        const int t  = w * 32 + mt * 16 + lr;
        const int tc = t < NT0 ? t : NT0 - 1;
#pragma unroll
        for (int kk = 0; kk < 2; ++kk) {
            const int cb = kk * 32 + lg * 8;        // k-base 0..56
            const int cc = cb <= 32 ? cb : 0;       // clamp (row is 40 wide)
            const float4* pw = (const float4*)(W11 + tc * ND1 + cc);
            const float4 w0 = pw[0], w1 = pw[1];
            const bool v = (t < NT0) && (cb <= 32); // valid cols only
            short8 f;
            f[0] = v ? (short)f2bf(w0.x) : (short)0;
            f[1] = v ? (short)f2bf(w0.y) : (short)0;
            f[2] = v ? (short)f2bf(w0.z) : (short)0;
            f[3] = v ? (short)f2bf(w0.w) : (short)0;
            f[4] = v ? (short)f2bf(w1.x) : (short)0;
            f[5] = v ? (short)f2bf(w1.y) : (short)0;
            f[6] = v ? (short)f2bf(w1.z) : (short)0;
            f[7] = v ? (short)f2bf(w1.w) : (short)0;
            afr[mt][kk] = f;
        }
    }

    __syncthreads();

    // ---------------- phase 2: MFMA + fused relu/fc4 ----------------------
    float st[2][4][4];          // [m-tile][n-tile][reg] = st[t, b] fragments
#pragma unroll
    for (int mt = 0; mt < 2; ++mt)
#pragma unroll
        for (int nt = 0; nt < 4; ++nt)
#pragma unroll
            for (int r = 0; r < 4; ++r) st[mt][nt][r] = 0.f;

    const short8 zfrag = {0, 0, 0, 0, 0, 0, 0, 0};

#pragma unroll
    for (int u = 0; u < NT1; ++u) {
        const float fu = fc4_w[u];                  // wave-uniform scalar
        float bv[2][4];
#pragma unroll
        for (int mt = 0; mt < 2; ++mt)
#pragma unroll
            for (int r = 0; r < 4; ++r) {
                const int t = w * 32 + mt * 16 + lg * 4 + r;
                bv[mt][r] = (t < NT0) ? bias1[t * NT1 + u] : 0.f;
            }
        const unsigned short* Yu = &Ybf[u * (NBW * PK)];
#pragma unroll
        for (int nt = 0; nt < 4; ++nt) {
            const short8 b0 = *(const short8*)&Yu[(nt * 16 + lr) * PK + lg * 8];
            short8 b1 = zfrag;                       // k-tile 1: cols 32..39
            if (lg == 0)                             // only k-group 0 is real
                b1 = *(const short8*)&Yu[(nt * 16 + lr) * PK + 32];
#pragma unroll
            for (int mt = 0; mt < 2; ++mt) {
                f32x4 z = {0.f, 0.f, 0.f, 0.f};
                z = __builtin_amdgcn_mfma_f32_16x16x32_bf16(afr[mt][0], b0, z, 0, 0, 0);
                z = __builtin_amdgcn_mfma_f32_16x16x32_bf16(afr[mt][1], b1, z, 0, 0, 0);
#pragma unroll
                for (int r = 0; r < 4; ++r)
                    st[mt][nt][r] += fu * fmaxf(z[r] + bv[mt][r], 0.f);
            }
        }
    }

    // ---------------- epilogue: out[o,b] = sum_t W12[o,t]*st[t,b] ---------
    float w12v[NO0][2][4];
#pragma unroll
    for (int o = 0; o < NO0; ++o)
#pragma unroll
        for (int mt = 0; mt < 2; ++mt)
#pragma unroll
            for (int r = 0; r < 4; ++r) {
                const int t = w * 32 + mt * 16 + lg * 4 + r;
                w12v[o][mt][r] = (t < NT0) ? W12[o * NT0 + t] : 0.f;
            }

    float po[4][NO0];
#pragma unroll
    for (int nt = 0; nt < 4; ++nt)
#pragma unroll
        for (int o = 0; o < NO0; ++o) {
            float a = 0.f;
#pragma unroll
            for (int mt = 0; mt < 2; ++mt)
#pragma unroll
                for (int r = 0; r < 4; ++r)
                    a = fmaf(w12v[o][mt][r], st[mt][nt][r], a);
            a += __shfl_xor(a, 16, 64);   // reduce over k-groups (t-rows)
            a += __shfl_xor(a, 32, 64);
            po[nt][o] = a;
        }

    if (l < 16) {
#pragma unroll
        for (int nt = 0; nt < 4; ++nt)
#pragma unroll
            for (int o = 0; o < NO0; ++o)
                redL[(w * NO0 + o) * NBW + nt * 16 + l] = po[nt][o];
    }
    __syncthreads();

    if (tid < NO0 * NBW) {                 // 192 threads
        const int o  = tid >> 6;
        const int bc = tid & 63;
        const float s = redL[(0 * NO0 + o) * NBW + bc]
                      + redL[(1 * NO0 + o) * NBW + bc]
                      + redL[(2 * NO0 + o) * NBW + bc]
                      + redL[(3 * NO0 + o) * NBW + bc]
                      + bias2[o];
        out[(size_t)(wg * NBW + bc) * NO0 + o] = s;
    }
}

extern "C" void kernel_launch(void* const* d_in, const int* in_sizes, int n_in,
                              void* d_out, int out_size, void* d_ws, size_t ws_size,
                              hipStream_t stream) {
    const float* x      = (const float*)d_in[0];
    const float* W11    = (const float*)d_in[1];
    const float* fc2_w  = (const float*)d_in[2];
    const float* bias1  = (const float*)d_in[3];
    const float* W12    = (const float*)d_in[4];
    const float* fc4_w  = (const float*)d_in[5];
    const float* bias2  = (const float*)d_in[6];
    float* out = (float*)d_out;

    const int blocks = NB / NBW;   // 2048
    BL_36721970381090_kernel<<<blocks, 256, 0, stream>>>(
        x, W11, fc2_w, bias1, W12, fc4_w, bias2, out);
}